// Round 1
// baseline (138.635 us; speedup 1.0000x reference)
//
#include <hip/hip_runtime.h>

typedef __bf16 bf16_t;
typedef bf16_t bf16x8 __attribute__((ext_vector_type(8)));
typedef bf16_t bf16x4 __attribute__((ext_vector_type(4)));
typedef float f32x4 __attribute__((ext_vector_type(4)));

#define M_TOK 32768
#define NWIN 128
#define WIN  256

typedef __attribute__((address_space(3))) void* as3p;
typedef const __attribute__((address_space(1))) void* as1p;

__device__ __forceinline__ void gll16(const void* g, void* l) {
    __builtin_amdgcn_global_load_lds((as1p)g, (as3p)l, 16, 0, 0);
}

__device__ __forceinline__ bf16x8 cvt8(f32x4 a, f32x4 b) {
    bf16x8 o;
    o[0] = (bf16_t)a[0]; o[1] = (bf16_t)a[1]; o[2] = (bf16_t)a[2]; o[3] = (bf16_t)a[3];
    o[4] = (bf16_t)b[0]; o[5] = (bf16_t)b[1]; o[6] = (bf16_t)b[2]; o[7] = (bf16_t)b[3];
    return o;
}

// fp32 -> bf16 convert for X (8388608), w_qkv (196608), w_proj (65536). 8 elem/thread.
__global__ __launch_bounds__(256) void convpack(
    const float* __restrict__ X, const float* __restrict__ wq, const float* __restrict__ wp,
    bf16_t* __restrict__ Xb, bf16_t* __restrict__ wqb, bf16_t* __restrict__ wpb)
{
    long i8 = ((long)blockIdx.x * 256 + threadIdx.x) * 8;
    const float* s; bf16_t* dst; long idx;
    if (i8 < 8388608)      { s = X;  dst = Xb;  idx = i8; }
    else if (i8 < 8585216) { s = wq; dst = wqb; idx = i8 - 8388608; }
    else                   { s = wp; dst = wpb; idx = i8 - 8585216; }
    f32x4 v0 = *(const f32x4*)(s + idx);
    f32x4 v1 = *(const f32x4*)(s + idx + 4);
    *(bf16x8*)(dst + idx) = cvt8(v0, v1);
}

// GEMM1: QKV = relu_qk(Xb @ Wqkv^T), both bf16 [*,256].
// Output layout: QKV[nblk][tok][32] with nblk = n>>5 (0..7 q, 8..15 k, 16..23 v).
// LDS: 128B rows, XOR granule swizzle (pre-swizzled global src, swizzled ds_read).
__global__ __launch_bounds__(256) void gemm1_qkv(
    const bf16_t* __restrict__ Xb,
    const bf16_t* __restrict__ Wb,
    bf16_t* __restrict__ QKV)
{
    __shared__ __align__(16) bf16_t As[128][64];   // [m][k], 128B rows
    __shared__ __align__(16) bf16_t Bs[128][64];   // [n][k]

    const int tid = threadIdx.x;
    const int lane = tid & 63;
    const int wv = tid >> 6;
    const int wm = wv >> 1, wn = wv & 1;
    // supertile swizzle: 8 m-blocks x 6 n-blocks; stride-8 ids -> same XCD shares A panel
    const int id = blockIdx.x;
    const int sg = id / 48, wsub = id % 48;
    const int m0 = (sg * 8 + (wsub & 7)) * 128;
    const int n0 = (wsub >> 3) * 128;
    const int r = lane & 15, q = lane >> 4;
    const int lrow = lane >> 3;                    // 0..7 row within 1KB store
    const int lg8 = ((lane & 7) ^ lrow) * 8;       // pre-swizzled k-elem offset
    const int rx = r & 7;                          // row&7 for read-side swizzle

    f32x4 acc[4][4] = {};

    for (int kc = 0; kc < 256; kc += 64) {
#pragma unroll
        for (int g = 0; g < 4; ++g) {
            const int rb = wv * 32 + g * 8;        // 8 rows x 128B = 1KB per inst
            gll16(Xb + (size_t)(m0 + rb + lrow) * 256 + kc + lg8, &As[rb][0]);
            gll16(Wb + (size_t)(n0 + rb + lrow) * 256 + kc + lg8, &Bs[rb][0]);
        }
        __syncthreads();

#pragma unroll
        for (int kk = 0; kk < 64; kk += 32) {
            const int ax8 = (((kk >> 3) + q) ^ rx) * 8;   // swizzled granule
            bf16x8 a[4], b[4];
#pragma unroll
            for (int i = 0; i < 4; ++i)
                a[i] = *(const bf16x8*)&As[wm * 64 + i * 16 + r][ax8];
#pragma unroll
            for (int j = 0; j < 4; ++j)
                b[j] = *(const bf16x8*)&Bs[wn * 64 + j * 16 + r][ax8];
#pragma unroll
            for (int i = 0; i < 4; ++i)
#pragma unroll
                for (int j = 0; j < 4; ++j)   // swapped: col-field->m(r), row-field->n(q*4+reg)
                    acc[i][j] = __builtin_amdgcn_mfma_f32_16x16x32_bf16(b[j], a[i], acc[i][j], 0, 0, 0);
        }
        __syncthreads();
    }

#pragma unroll
    for (int i = 0; i < 4; ++i) {
        const int rowg = m0 + wm * 64 + i * 16 + r;
#pragma unroll
        for (int j = 0; j < 4; ++j) {
            const int nb = n0 + wn * 64 + j * 16 + q * 4;
            const int nblk = nb >> 5, d = nb & 31;
            bf16x4 o;
#pragma unroll
            for (int reg = 0; reg < 4; ++reg) {
                float v = acc[i][j][reg];
                if (nblk < 16) v = fmaxf(v, 0.0f);   // relu on q,k (n<512)
                o[reg] = (bf16_t)v;
            }
            *(bf16x4*)&QKV[((size_t)nblk * M_TOK + rowg) * 32 + d] = o;
        }
    }
}

// GEMM2: Out = Y @ Wproj^T + b, Y bf16 [32768,256] row-major, Out fp32.
// Tile 128x64 (grid 1024 -> 4 blocks/CU), same swizzled-LDS scheme.
__global__ __launch_bounds__(256) void gemm2_proj(
    const bf16_t* __restrict__ Y,
    const bf16_t* __restrict__ Wb,
    const float* __restrict__ bias,
    float* __restrict__ Out)
{
    __shared__ __align__(16) bf16_t As[128][64];
    __shared__ __align__(16) bf16_t Bs[64][64];

    const int tid = threadIdx.x;
    const int lane = tid & 63;
    const int wv = tid >> 6;
    const int wm = wv >> 1, wn = wv & 1;
    const int id = blockIdx.x;
    const int sg = id / 32, wsub = id % 32;      // supertile: 8m x 4n
    const int m0 = (sg * 8 + (wsub & 7)) * 128;
    const int n0 = (wsub >> 3) * 64;
    const int r = lane & 15, q = lane >> 4;
    const int lrow = lane >> 3;
    const int lg8 = ((lane & 7) ^ lrow) * 8;
    const int rx = r & 7;

    f32x4 acc[4][2] = {};

    for (int kc = 0; kc < 256; kc += 64) {
#pragma unroll
        for (int g = 0; g < 4; ++g) {
            const int rb = wv * 32 + g * 8;
            gll16(Y + (size_t)(m0 + rb + lrow) * 256 + kc + lg8, &As[rb][0]);
        }
#pragma unroll
        for (int g = 0; g < 2; ++g) {
            const int rb = wv * 16 + g * 8;
            gll16(Wb + (size_t)(n0 + rb + lrow) * 256 + kc + lg8, &Bs[rb][0]);
        }
        __syncthreads();

#pragma unroll
        for (int kk = 0; kk < 64; kk += 32) {
            const int ax8 = (((kk >> 3) + q) ^ rx) * 8;
            bf16x8 a[4], b[2];
#pragma unroll
            for (int i = 0; i < 4; ++i)
                a[i] = *(const bf16x8*)&As[wm * 64 + i * 16 + r][ax8];
#pragma unroll
            for (int j = 0; j < 2; ++j)
                b[j] = *(const bf16x8*)&Bs[wn * 32 + j * 16 + r][ax8];
#pragma unroll
            for (int i = 0; i < 4; ++i)
#pragma unroll
                for (int j = 0; j < 2; ++j)
                    acc[i][j] = __builtin_amdgcn_mfma_f32_16x16x32_bf16(b[j], a[i], acc[i][j], 0, 0, 0);
        }
        __syncthreads();
    }

#pragma unroll
    for (int i = 0; i < 4; ++i) {
        const int rowg = m0 + wm * 64 + i * 16 + r;
#pragma unroll
        for (int j = 0; j < 2; ++j) {
            const int nb = n0 + wn * 32 + j * 16 + q * 4;
            f32x4 bi = *(const f32x4*)(bias + nb);
            f32x4 o;
#pragma unroll
            for (int reg = 0; reg < 4; ++reg) o[reg] = acc[i][j][reg] + bi[reg];
            *(f32x4*)&Out[(size_t)rowg * 256 + nb] = o;
        }
    }
}

// Fused per-(window,head) linear attention on blocked QKV layout.
__global__ __launch_bounds__(256) void kvy_kernel(
    const bf16_t* __restrict__ QKV,   // [24][32768][32]
    const int* __restrict__ offsets,
    const int* __restrict__ counts,
    bf16_t* __restrict__ Y)           // [32768,256] row-major
{
    const int w = blockIdx.x;
    const int h = blockIdx.y;
    const int is64 = (counts[1] == 0) ? 1 : 0;
    const int off = offsets[w << is64];
    const int tid = threadIdx.x;
    const int lane = tid & 63;
    const int wv = tid >> 6;

    __shared__ __align__(16) bf16_t KT[32 * 264];   // KT[c][t]
    __shared__ __align__(16) bf16_t VT[32 * 264];   // VT[d][t]
    __shared__ __align__(16) bf16_t KVT[32 * 40];   // KVT[d][c]
    __shared__ float sbuf[32];
    __shared__ float spart[32 * 8];
    __shared__ float zinv[WIN];

    // P0: stage K,V transposed (thread = token); fully coalesced 64B/token reads
    {
        const int t = tid;
        const bf16_t* kp = QKV + ((size_t)(8 + h) * M_TOK + off + t) * 32;
        const bf16_t* vp = QKV + ((size_t)(16 + h) * M_TOK + off + t) * 32;
        bf16_t ka[32], va[32];
#pragma unroll
        for (int u = 0; u < 4; ++u) {
            bf16x8 kk = *(const bf16x8*)(kp + u * 8);
            bf16x8 vvv = *(const bf16x8*)(vp + u * 8);
#pragma unroll
            for (int j = 0; j < 8; ++j) { ka[u * 8 + j] = kk[j]; va[u * 8 + j] = vvv[j]; }
        }
#pragma unroll
        for (int c = 0; c < 32; ++c) {
            KT[c * 264 + t] = ka[c];
            VT[c * 264 + t] = va[c];
        }
    }
    __syncthreads();

    // P1a: s partials
    {
        const int c = tid >> 3;
        const int tc = (tid & 7) * 32;
        float ps = 0.f;
#pragma unroll
        for (int u = 0; u < 4; ++u) {
            bf16x8 kk = *(const bf16x8*)(&KT[c * 264 + tc + u * 8]);
#pragma unroll
            for (int j = 0; j < 8; ++j) ps += (float)kk[j];
        }
        spart[c * 8 + (tid & 7)] = ps;
    }
    // P1b: KV = K^T V via MFMA (col-field->d, row-field->c); store KVT[d][c]
    {
        const int i = wv >> 1, j = wv & 1;
        const int r = lane & 15, q = lane >> 4;
        f32x4 acc = {};
#pragma unroll
        for (int ch = 0; ch < 8; ++ch) {
            bf16x8 af = *(const bf16x8*)(&KT[(i * 16 + r) * 264 + ch * 32 + q * 8]);
            bf16x8 bf_ = *(const bf16x8*)(&VT[(j * 16 + r) * 264 + ch * 32 + q * 8]);
            acc = __builtin_amdgcn_mfma_f32_16x16x32_bf16(af, bf_, acc, 0, 0, 0);
        }
        bf16x4 kv4;
#pragma unroll
        for (int reg = 0; reg < 4; ++reg) kv4[reg] = (bf16_t)acc[reg];
        *(bf16x4*)(&KVT[(j * 16 + r) * 40 + i * 16 + q * 4]) = kv4;
    }
    __syncthreads();
    if (tid < 32) {
        float s = 0.f;
#pragma unroll
        for (int u = 0; u < 8; ++u) s += spart[tid * 8 + u];
        sbuf[tid] = s;
    }
    __syncthreads();

    // P2: zinv[t]
    {
        const int t = tid;
        const bf16_t* qp = QKV + ((size_t)h * M_TOK + off + t) * 32;
        float z = 0.f;
#pragma unroll
        for (int u = 0; u < 4; ++u) {
            bf16x8 qq = *(const bf16x8*)(qp + u * 8);
#pragma unroll
            for (int j = 0; j < 8; ++j) z += (float)qq[j] * sbuf[u * 8 + j];
        }
        zinv[t] = 1.0f / (z + 1e-3f);
    }
    __syncthreads();

    // P3: y = (Q.KV)*zinv via swapped MFMA (col-field->t, row-field->d): bf16x4 stores
    {
        const int r = lane & 15, q = lane >> 4;
        bf16x8 b0 = *(const bf16x8*)(&KVT[(r) * 40 + q * 8]);        // d=r   (j=0)
        bf16x8 b1 = *(const bf16x8*)(&KVT[(16 + r) * 40 + q * 8]);   // d=16+r(j=1)
#pragma unroll
        for (int u = 0; u < 4; ++u) {
            const int mi = wv * 4 + u;
            const bf16_t* ap = QKV + ((size_t)h * M_TOK + off + mi * 16 + r) * 32 + q * 8;
            bf16x8 af = *(const bf16x8*)ap;
            f32x4 acc0 = {}, acc1 = {};
            acc0 = __builtin_amdgcn_mfma_f32_16x16x32_bf16(b0, af, acc0, 0, 0, 0);
            acc1 = __builtin_amdgcn_mfma_f32_16x16x32_bf16(b1, af, acc1, 0, 0, 0);
            const int tkn = mi * 16 + r;
            const float zi = zinv[tkn];
            bf16_t* yp = Y + (size_t)(off + tkn) * 256 + h * 32;
            bf16x4 o0, o1;
#pragma unroll
            for (int reg = 0; reg < 4; ++reg) {
                o0[reg] = (bf16_t)(acc0[reg] * zi);
                o1[reg] = (bf16_t)(acc1[reg] * zi);
            }
            *(bf16x4*)(yp + q * 4) = o0;
            *(bf16x4*)(yp + 16 + q * 4) = o1;
        }
    }
}

extern "C" void kernel_launch(void* const* d_in, const int* in_sizes, int n_in,
                              void* d_out, int out_size, void* d_ws, size_t ws_size,
                              hipStream_t stream) {
    const float* x      = (const float*)d_in[0];
    const float* w_qkv  = (const float*)d_in[1];
    const float* w_proj = (const float*)d_in[2];
    const float* b_proj = (const float*)d_in[3];
    const int*   offs   = (const int*)d_in[4];
    const int*   cnts   = (const int*)d_in[5];

    char* ws = (char*)d_ws;
    bf16_t* QKV = (bf16_t*)ws;                    // 24*32768*32*2 = 50331648 B
    bf16_t* Y   = (bf16_t*)(ws + 50331648);       // 16777216 B
    bf16_t* Xb  = Y;                              // alias: Xb dead before kvy writes Y
    bf16_t* Wqb = (bf16_t*)(ws + 67108864);       //   393216 B
    bf16_t* Wpb = (bf16_t*)(ws + 67502080);       //   131072 B
    float*  out = (float*)d_out;

    // 0) X + weights fp32 -> bf16
    convpack<<<4224, 256, 0, stream>>>(x, w_qkv, w_proj, Xb, Wqb, Wpb);

    // 1) QKV gemm (blocked output layout)
    gemm1_qkv<<<1536, 256, 0, stream>>>(Xb, Wqb, QKV);

    // 2+3) fused per-(window,head) KV + normalize (overwrites Xb with Y)
    kvy_kernel<<<dim3(NWIN, 8), 256, 0, stream>>>(QKV, offs, cnts, Y);

    // 4) proj gemm, fp32 out
    gemm2_proj<<<1024, 256, 0, stream>>>(Y, Wpb, b_proj, out);
}